// Round 15
// baseline (2057.953 us; speedup 1.0000x reference)
//
#include <hip/hip_runtime.h>
#include <stdint.h>
#include <stddef.h>

typedef _Float16 f16;
typedef _Float16 f16x2 __attribute__((ext_vector_type(2)));
typedef _Float16 f16x4 __attribute__((ext_vector_type(4)));
typedef _Float16 f16x8 __attribute__((ext_vector_type(8)));
typedef float f32x16 __attribute__((ext_vector_type(16)));

#define INNER_SZ 4225
#define NQ 164          // ksteps: 160 quad (sym-folded, row-rounded) + 4 linear
#define XSTR 72
#define NPH 41          // phases of 4 ksteps

// ---------------- prep: symmetric fold + granule-packed f16 (verified R9-R14) ----
// Wf2 layout: [q][2048B] = [q][ng(2)][64 granules(16B)][8 f16], granule G = 2c+h.
__global__ __launch_bounds__(256) void cm_prep(const float* __restrict__ W,
                                               const float* __restrict__ bias,
                                               f16* __restrict__ Wf2,
                                               float* __restrict__ cvec) {
  int idx = blockIdx.x * 256 + threadIdx.x;
  if (idx < NQ * 1024) {
    int q   = idx >> 10;
    int r10 = idx & 1023;
    int ngh = r10 >> 9;
    int rr  = r10 & 511;
    int G   = rr >> 3;
    int e   = rr & 7;
    int c = G >> 1, hh = G & 1;
    int o = ngh * 32 + c;
    int kl = hh * 8 + e;
    float v = 0.f;
    if (q < 160) {
      int b, start;
      if (q < 16)      { b = 0; start = 0;  }
      else if (q < 48) { b = 1; start = 16; }
      else if (q < 96) { b = 2; start = 48; }
      else             { b = 3; start = 96; }
      int rel = q - start;
      int i = 16 * b + rel / (b + 1);
      int s = rel % (b + 1);
      int j = s * 16 + kl;
      if (j < i)
        v = W[o * INNER_SZ + (i + 1) * 65 + (j + 1)] +
            W[o * INNER_SZ + (j + 1) * 65 + (i + 1)];
      else if (j == i)
        v = W[o * INNER_SZ + (i + 1) * 65 + (i + 1)];
    } else {
      int j = (q - 160) * 16 + kl;
      v = W[o * INNER_SZ + (j + 1)] + W[o * INNER_SZ + (j + 1) * 65];
    }
    Wf2[idx] = (f16)v;
  }
  if (idx < 64) cvec[idx] = W[idx * INNER_SZ] + bias[idx];
}

// global -> LDS direct, 16B/lane (wave-uniform dest base + lane*16)
__device__ inline void gload_lds16(const void* gp, void* lp) {
  __builtin_amdgcn_global_load_lds(
      (const __attribute__((address_space(1))) uint32_t*)(uintptr_t)gp,
      (__attribute__((address_space(3))) uint32_t*)(uintptr_t)lp, 16, 0, 0);
}

__device__ __forceinline__ f16x8 mulsp(f16x2 sp, f16x8 wv) {
  f16x8 r;
#pragma unroll
  for (int e = 0; e < 4; ++e)
    ((f16x2*)&r)[e] = sp * ((const f16x2*)&wv)[e];
  return r;
}

// ---------------- main fused kernel (R14 structure; K-loop x2 ABLATION) ----------
// DIAGNOSTIC ROUND: the K-loop runs twice (acc halved at the end, same output).
// Measures marginal K-work cost vs fixed overhead + lifts cm_main above the
// harness fill kernels so rocprof top-5 shows its counters.
__global__ __launch_bounds__(512, 4) void cm_main(
    const float* __restrict__ x, const f16* __restrict__ Wf2,
    const float* __restrict__ cvec, const float* __restrict__ gamma,
    const float* __restrict__ beta, float* __restrict__ out) {
  __shared__ __align__(16) union SM {
    struct { f16 ring[3][4096]; f16 xs[128 * XSTR]; } k;  // 24 KB + 18 KB
    float yt[8192];                                       // 32 KB epilogue (aliases)
  } sm;

  const int tid = threadIdx.x;
  const int lane = tid & 63;
  const int w = tid >> 6;
  const int rowg = w & 3;
  const int ch = w >> 2;
  const int c31 = lane & 31;
  const int h = lane >> 5;
  const long mbase = (long)blockIdx.x * 128;

  const char* wsrc = (const char*)Wf2 + lane * 16;
  char* ringb = (char*)&sm.k.ring[0][0];

  // wave w stages bytes [w*1024, w*1024+1024) of phase slab T into slot addr D
#define STAGE(T, D)                                                         \
  gload_lds16(wsrc + (size_t)(4 * (T) + (w >> 1)) * 2048 + (w & 1) * 1024,  \
              (D) + w * 1024)

  STAGE(0, ringb + 0 * 8192);
  STAGE(1, ringb + 1 * 8192);

  // ---- x tile -> LDS f16 [128][72] ----
#pragma unroll
  for (int it = 0; it < 4; ++it) {
    int idx = it * 2048 + tid * 4;
    int row = idx >> 6, col = idx & 63;
    const float4 v = *(const float4*)(x + (size_t)(mbase + row) * 64 + col);
    f16x4 hv = {(f16)v.x, (f16)v.y, (f16)v.z, (f16)v.w};
    *(f16x4*)(sm.k.xs + row * XSTR + col) = hv;
  }
  __syncthreads();   // xs visible + stages 0,1 landed (prologue-only drain)

  const int r0 = rowg * 32 + c31;
  f16x8 xw[4];
#pragma unroll
  for (int s = 0; s < 4; ++s)
    xw[s] = *(const f16x8*)(sm.k.xs + r0 * XSTR + s * 16 + h * 8);
#pragma unroll
  for (int s = 0; s < 4; ++s)   // pin windows in registers
    asm volatile("" : "+v"(xw[s]));

  const int bfo = ch * 1024 + (2 * c31 + h) * 16;   // B-frag offset within kstep slab

  f32x16 acc = (f32x16)(0.0f);
  f16x2 sp = {};

  // ---- K loop x2: 82 global phases (pp = rep*41 + p), ring slot = pp%3 ----
#pragma unroll 1
  for (int rep = 0; rep < 2; ++rep) {
    const int s0 = (rep == 0) ? 0 : 2;               // (rep*41) % 3
    uint32_t un = *(const uint16_t*)(sm.k.xs + r0 * XSTR);   // x_i(0) prefetch
#pragma unroll
    for (int p = 0; p < NPH; ++p) {
      const bool last = (p == NPH - 1);
      if (last) {
        if (rep == 1) asm volatile("s_waitcnt vmcnt(0)" ::: "memory");
        else          asm volatile("s_waitcnt vmcnt(1)" ::: "memory");
      } else {
        asm volatile("s_waitcnt vmcnt(1)" ::: "memory");
      }
      __builtin_amdgcn_s_barrier();
      asm volatile("" ::: "memory");
      __builtin_amdgcn_sched_barrier(0);
      if (rep == 0 || p < NPH - 2) {                 // pp+2 < 82
        int sl2 = s0 + (p + 2) % 3; if (sl2 >= 3) sl2 -= 3;
        STAGE((p + 2) % NPH, ringb + sl2 * 8192);
      }
      int slc = s0 + p % 3; if (slc >= 3) slc -= 3;
      const char* rb = ringb + slc * 8192;
      __builtin_amdgcn_s_setprio(1);
#pragma unroll
      for (int kk = 0; kk < 4; ++kk) {
        const int q = 4 * p + kk;
        int i, s, lin;
        if (q >= 160) { i = 64; s = q - 160; lin = 1; }
        else {
          int b = (q < 16) ? 0 : (q < 48) ? 1 : (q < 96) ? 2 : 3;
          int st = (b == 0) ? 0 : (b == 1) ? 16 : (b == 2) ? 48 : 96;
          int rel = q - st;
          i = 16 * b + rel / (b + 1);
          s = rel % (b + 1);
          lin = 0;
        }
        bool newi;
        if (q == 0) newi = true;
        else if (lin) newi = false;
        else {
          int qp = q - 1;
          int bp = (qp < 16) ? 0 : (qp < 48) ? 1 : (qp < 96) ? 2 : 3;
          int stp = (bp == 0) ? 0 : (bp == 1) ? 16 : (bp == 2) ? 48 : 96;
          newi = (16 * bp + (qp - stp) / (bp + 1)) != i;
        }
        if (newi) {
          uint32_t u = un & 0xffffu;
          sp = __builtin_bit_cast(f16x2, u | (u << 16));
          if (i + 1 < 64)
            un = *(const uint16_t*)(sm.k.xs + r0 * XSTR + i + 1);
        }
        f16x8 bf = *(const f16x8*)(rb + kk * 2048 + bfo);
        f16x8 a = lin ? xw[s] : mulsp(sp, xw[s]);
        acc = __builtin_amdgcn_mfma_f32_32x32x16_f16(a, bf, acc, 0, 0, 0);
      }
      __builtin_amdgcn_s_setprio(0);
    }
  }

#pragma unroll
  for (int r = 0; r < 16; ++r) acc[r] *= 0.5f;   // undo the x2 accumulation

  // ---- epilogue: transpose via swizzled LDS (aliases ring+xs), LN, store ----
  __syncthreads();                 // all reads done -> safe to alias
  {
    const int cg = ch * 32 + c31;
    const int swz = (c31 & 7) << 4;
#pragma unroll
    for (int rq = 0; rq < 4; ++rq) {
      int b0 = cg * 512 + rowg * 128 + rq * 32 + h * 16;
      *(float4*)((char*)sm.yt + (b0 ^ swz)) =
          make_float4(acc[rq * 4 + 0], acc[rq * 4 + 1], acc[rq * 4 + 2], acc[rq * 4 + 3]);
    }
  }
  __syncthreads();

  // ---- LayerNorm: 256 threads, one (row, col-half) each ----
  if (tid < 256) {
    int row = tid >> 1, half = tid & 1;
    float y[32];
    float s = 0.f, qs = 0.f;
#pragma unroll
    for (int j = 0; j < 32; ++j) {
      int c = half * 32 + j;
      int byte = (c * 512 + row * 4) ^ ((c & 7) << 4);
      float v = *(const float*)((const char*)sm.yt + byte);
      v += cvec[c];
      y[j] = v;
      s += v; qs += v * v;
    }
    s  += __shfl_xor(s, 1);
    qs += __shfl_xor(qs, 1);
    float mean = s * 0.015625f;
    float var = qs * 0.015625f - mean * mean;
    float rstd = rsqrtf(var + 1e-6f);
#pragma unroll
    for (int j = 0; j < 32; ++j) {
      int c = half * 32 + j;
      y[j] = gamma[c] * (y[j] - mean) * rstd + beta[c];
    }
    float* op = out + (size_t)(mbase + row) * 64 + half * 32;
#pragma unroll
    for (int j4 = 0; j4 < 8; ++j4)
      *(float4*)(op + j4 * 4) =
          make_float4(y[j4 * 4 + 0], y[j4 * 4 + 1], y[j4 * 4 + 2], y[j4 * 4 + 3]);
  }
#undef STAGE
}

extern "C" void kernel_launch(void* const* d_in, const int* in_sizes, int n_in,
                              void* d_out, int out_size, void* d_ws, size_t ws_size,
                              hipStream_t stream) {
  const float* x     = (const float*)d_in[0];
  const float* W     = (const float*)d_in[1];
  const float* bias  = (const float*)d_in[2];
  const float* gamma = (const float*)d_in[3];
  const float* beta  = (const float*)d_in[4];
  float* out = (float*)d_out;

  f16* Wf2 = (f16*)d_ws;                                   // 164*1024*2 = 335872 B
  float* cvec = (float*)((char*)d_ws + NQ * 1024 * 2);     // 64 f32

  cm_prep<<<(NQ * 1024 + 255) / 256, 256, 0, stream>>>(W, bias, Wf2, cvec);
  cm_main<<<512, 512, 0, stream>>>(x, Wf2, cvec, gamma, beta, out);
}

// Round 16
// 39.210 us; speedup vs baseline: 52.4859x; 52.4859x over previous
//
#include <hip/hip_runtime.h>
#include <stdint.h>
#include <stddef.h>

typedef _Float16 f16;
typedef _Float16 f16x2 __attribute__((ext_vector_type(2)));
typedef _Float16 f16x4 __attribute__((ext_vector_type(4)));
typedef _Float16 f16x8 __attribute__((ext_vector_type(8)));
typedef float f32x16 __attribute__((ext_vector_type(16)));

#define INNER_SZ 4225
#define NQ 164          // real ksteps: 160 quad (sym-folded) + 4 linear
#define NQP 168         // padded to 21 phases x 8 ksteps (pad W = 0)
#define KPP 8           // ksteps per phase
#define NPH 21
#define XSTR 72

// ---------------- prep: symmetric fold + granule-packed f16 ----------------
// Wf2 layout: [q][2048B] = [q][ngh(2)][hh(2)][c(32)][e(8)] f16  (granule G = c + 32*hh)
// -> lane l of col-half ch reads byte ch*1024 + (l&31)*16 + (l>>5)*512: contiguous
//    16B/lane per half-wave = conflict-free ds_read_b128.
// q<160: quad row i, sub s: coeff[j = s*16 + hh*8 + e] (j<i: Wij+Wji; j==i: Wii; else 0)
// q in 160..163: linear terms; q >= 164: zero pad.
__global__ __launch_bounds__(256) void cm_prep(const float* __restrict__ W,
                                               const float* __restrict__ bias,
                                               f16* __restrict__ Wf2,
                                               float* __restrict__ cvec) {
  int idx = blockIdx.x * 256 + threadIdx.x;
  if (idx < NQP * 1024) {
    int q   = idx >> 10;
    int r10 = idx & 1023;
    int ngh = r10 >> 9;
    int rr  = r10 & 511;
    int hh  = rr >> 8;
    int c   = (rr >> 3) & 31;
    int e   = rr & 7;
    int o = ngh * 32 + c;
    int kl = hh * 8 + e;
    float v = 0.f;
    if (q < 160) {
      int b, start;
      if (q < 16)      { b = 0; start = 0;  }
      else if (q < 48) { b = 1; start = 16; }
      else if (q < 96) { b = 2; start = 48; }
      else             { b = 3; start = 96; }
      int rel = q - start;
      int i = 16 * b + rel / (b + 1);
      int s = rel % (b + 1);
      int j = s * 16 + kl;
      if (j < i)
        v = W[o * INNER_SZ + (i + 1) * 65 + (j + 1)] +
            W[o * INNER_SZ + (j + 1) * 65 + (i + 1)];
      else if (j == i)
        v = W[o * INNER_SZ + (i + 1) * 65 + (i + 1)];
    } else if (q < 164) {
      int j = (q - 160) * 16 + kl;
      v = W[o * INNER_SZ + (j + 1)] + W[o * INNER_SZ + (j + 1) * 65];
    }
    Wf2[idx] = (f16)v;
  }
  if (idx < 64) cvec[idx] = W[idx * INNER_SZ] + bias[idx];
}

// global -> LDS direct, 16B/lane (wave-uniform dest base + lane*16)
__device__ inline void gload_lds16(const void* gp, void* lp) {
  __builtin_amdgcn_global_load_lds(
      (const __attribute__((address_space(1))) uint32_t*)(uintptr_t)gp,
      (__attribute__((address_space(3))) uint32_t*)(uintptr_t)lp, 16, 0, 0);
}

__device__ __forceinline__ f16x8 mulsp(f16x2 sp, f16x8 wv) {
  f16x8 r;
#pragma unroll
  for (int e = 0; e < 4; ++e)
    ((f16x2*)&r)[e] = sp * ((const f16x2*)&wv)[e];
  return r;
}

// ---------------- main fused kernel ----------------
// grid 512 x 512 threads (8 waves). Block tile: 128 rows x 64 cols.
// Wave (rowg=w&3, ch=w>>2): rows rowg*32+[0,32), cols ch*32+[0,32).
// BIG phases: 8 ksteps (16KB W slab) per barrier -> 8 MFMA/wave/phase amortize
// the ~1600cy phase overhead. Ring-3 x 16KB, stage-2-ahead, counted vmcnt(2)
// before raw s_barrier (never drains mid-loop). Dual interleaved accumulators
// break the MFMA dep chain. All slot indices compile-time (R15 lesson).
__global__ __launch_bounds__(512, 4) void cm_main(
    const float* __restrict__ x, const f16* __restrict__ Wf2,
    const float* __restrict__ cvec, const float* __restrict__ gamma,
    const float* __restrict__ beta, float* __restrict__ out) {
  __shared__ __align__(16) union SM {
    struct { f16 ring[3][8192]; f16 xs[128 * XSTR]; } k;  // 48 KB + 18 KB
    float yt[8192];                                       // 32 KB epilogue (aliases)
  } sm;

  const int tid = threadIdx.x;
  const int lane = tid & 63;
  const int w = tid >> 6;
  const int rowg = w & 3;
  const int ch = w >> 2;
  const int c31 = lane & 31;
  const int h = lane >> 5;
  const long mbase = (long)blockIdx.x * 128;

  const char* wsrc = (const char*)Wf2 + lane * 16;
  char* ringb = (char*)&sm.k.ring[0][0];

  // wave w stages kstep (8*P + w): 2KB as two 1KB DMAs; linear both sides
#define STAGE(P)                                                            \
  do {                                                                      \
    const char* s_ = wsrc + (size_t)(8 * (P) + w) * 2048;                   \
    char* d_ = ringb + ((P) % 3) * 16384 + w * 2048;                        \
    gload_lds16(s_, d_);                                                    \
    gload_lds16(s_ + 1024, d_ + 1024);                                      \
  } while (0)

  STAGE(0);
  STAGE(1);

  // ---- x tile -> LDS f16 [128][72] ----
#pragma unroll
  for (int it = 0; it < 4; ++it) {
    int idx = it * 2048 + tid * 4;
    int row = idx >> 6, col = idx & 63;
    const float4 v = *(const float4*)(x + (size_t)(mbase + row) * 64 + col);
    f16x4 hv = {(f16)v.x, (f16)v.y, (f16)v.z, (f16)v.w};
    *(f16x4*)(sm.k.xs + row * XSTR + col) = hv;
  }
  __syncthreads();   // xs visible + stages 0,1 landed (prologue-only full drain)

  const int r0 = rowg * 32 + c31;
  f16x8 xw[4];
#pragma unroll
  for (int s = 0; s < 4; ++s)
    xw[s] = *(const f16x8*)(sm.k.xs + r0 * XSTR + s * 16 + h * 8);
#pragma unroll
  for (int s = 0; s < 4; ++s)
    asm volatile("" : "+v"(xw[s]));     // pin windows in registers

  // conflict-free B-frag offset: contiguous 16B/lane per half-wave
  const int bfo = ch * 1024 + c31 * 16 + h * 512;

  f32x16 accA = (f32x16)(0.0f);
  f32x16 accB = (f32x16)(0.0f);
  uint32_t un = *(const uint16_t*)(sm.k.xs + r0 * XSTR);   // x_i(0) prefetch
  f16x2 sp = {};

  // ---- K loop: 21 phases x 8 ksteps ----
#pragma unroll
  for (int p = 0; p < NPH; ++p) {
    if (p < NPH - 1) asm volatile("s_waitcnt vmcnt(2)" ::: "memory");
    else             asm volatile("s_waitcnt vmcnt(0)" ::: "memory");
    __builtin_amdgcn_s_barrier();
    asm volatile("" ::: "memory");
    __builtin_amdgcn_sched_barrier(0);
    if (p + 2 < NPH) STAGE(p + 2);
    const char* rb = ringb + (p % 3) * 16384;
    __builtin_amdgcn_s_setprio(1);
#pragma unroll
    for (int kk = 0; kk < KPP; ++kk) {
      const int q = 8 * p + kk;             // 0..167 (>=164: zero pad)
      int i, s, lin;
      if (q >= 160) { i = 64; s = (q - 160) & 3; lin = 1; }
      else {
        int b = (q < 16) ? 0 : (q < 48) ? 1 : (q < 96) ? 2 : 3;
        int st = (b == 0) ? 0 : (b == 1) ? 16 : (b == 2) ? 48 : 96;
        int rel = q - st;
        i = 16 * b + rel / (b + 1);
        s = rel % (b + 1);
        lin = 0;
      }
      bool newi;
      if (q == 0) newi = true;
      else if (lin) newi = false;
      else {
        int qp = q - 1;
        int bp = (qp < 16) ? 0 : (qp < 48) ? 1 : (qp < 96) ? 2 : 3;
        int stp = (bp == 0) ? 0 : (bp == 1) ? 16 : (bp == 2) ? 48 : 96;
        newi = (16 * bp + (qp - stp) / (bp + 1)) != i;
      }
      if (newi) {
        uint32_t u = un & 0xffffu;
        sp = __builtin_bit_cast(f16x2, u | (u << 16));
        if (i + 1 < 64)
          un = *(const uint16_t*)(sm.k.xs + r0 * XSTR + i + 1);
      }
      f16x8 bf = *(const f16x8*)(rb + kk * 2048 + bfo);
      f16x8 a = lin ? xw[s] : mulsp(sp, xw[s]);
      if (kk & 1) accB = __builtin_amdgcn_mfma_f32_32x32x16_f16(a, bf, accB, 0, 0, 0);
      else        accA = __builtin_amdgcn_mfma_f32_32x32x16_f16(a, bf, accA, 0, 0, 0);
    }
    __builtin_amdgcn_s_setprio(0);
  }

  f32x16 acc;
#pragma unroll
  for (int r = 0; r < 16; ++r) acc[r] = accA[r] + accB[r];

  // ---- epilogue: transpose via swizzled LDS (aliases ring+xs), LN, store ----
  __syncthreads();                 // all reads done -> safe to alias
  {
    const int cg = ch * 32 + c31;
    const int swz = (c31 & 7) << 4;
#pragma unroll
    for (int rq = 0; rq < 4; ++rq) {
      int b0 = cg * 512 + rowg * 128 + rq * 32 + h * 16;
      *(float4*)((char*)sm.yt + (b0 ^ swz)) =
          make_float4(acc[rq * 4 + 0], acc[rq * 4 + 1], acc[rq * 4 + 2], acc[rq * 4 + 3]);
    }
  }
  __syncthreads();

  // ---- LayerNorm: 256 threads, one (row, col-half) each ----
  if (tid < 256) {
    int row = tid >> 1, half = tid & 1;
    float y[32];
    float s = 0.f, qs = 0.f;
#pragma unroll
    for (int j = 0; j < 32; ++j) {
      int c = half * 32 + j;
      int byte = (c * 512 + row * 4) ^ ((c & 7) << 4);
      float v = *(const float*)((const char*)sm.yt + byte);
      v += cvec[c];
      y[j] = v;
      s += v; qs += v * v;
    }
    s  += __shfl_xor(s, 1);
    qs += __shfl_xor(qs, 1);
    float mean = s * 0.015625f;
    float var = qs * 0.015625f - mean * mean;
    float rstd = rsqrtf(var + 1e-6f);
#pragma unroll
    for (int j = 0; j < 32; ++j) {
      int c = half * 32 + j;
      y[j] = gamma[c] * (y[j] - mean) * rstd + beta[c];
    }
    float* op = out + (size_t)(mbase + row) * 64 + half * 32;
#pragma unroll
    for (int j4 = 0; j4 < 8; ++j4)
      *(float4*)(op + j4 * 4) =
          make_float4(y[j4 * 4 + 0], y[j4 * 4 + 1], y[j4 * 4 + 2], y[j4 * 4 + 3]);
  }
#undef STAGE
}

extern "C" void kernel_launch(void* const* d_in, const int* in_sizes, int n_in,
                              void* d_out, int out_size, void* d_ws, size_t ws_size,
                              hipStream_t stream) {
  const float* x     = (const float*)d_in[0];
  const float* W     = (const float*)d_in[1];
  const float* bias  = (const float*)d_in[2];
  const float* gamma = (const float*)d_in[3];
  const float* beta  = (const float*)d_in[4];
  float* out = (float*)d_out;

  f16* Wf2 = (f16*)d_ws;                                   // 168*1024*2 = 344064 B
  float* cvec = (float*)((char*)d_ws + NQP * 1024 * 2);    // 64 f32

  cm_prep<<<(NQP * 1024 + 255) / 256, 256, 0, stream>>>(W, bias, Wf2, cvec);
  cm_main<<<512, 512, 0, stream>>>(x, Wf2, cvec, gamma, beta, out);
}